// Round 9
// baseline (208.471 us; speedup 1.0000x reference)
//
#include <hip/hip_runtime.h>
#include <hip/hip_fp16.h>
#include <math.h>

#define N_NODES 100000
#define N_EDGES 6400000
#define NF 128
#define NH 16
#define NB 128                          // nodes per bucket
#define KB 782                          // ceil(100000/128)
#define CAP 9216                        // static bucket capacity (mean 8192, sd ~90)

#define PT_THREADS 1024
#define PT_EPT 16
#define PT_TILE (PT_THREADS * PT_EPT)   // 16384 edges per block
#define PT_BLOCKS ((N_EDGES + PT_TILE - 1) / PT_TILE)  // 391
#define PT_WAVES (PT_THREADS / 64)      // 16

// ---------------- single-pass partition: LDS multisplit + coalesced burst run writes ----------------
__global__ __launch_bounds__(PT_THREADS) void k_part(const int* __restrict__ src, const int* __restrict__ dst,
                                                     int* __restrict__ bcur, unsigned* __restrict__ part) {
    __shared__ int lcnt[KB];            // per-bucket count in this tile
    __shared__ int lbase[KB];           // global write base (absolute)
    __shared__ int cur[PT_THREADS];     // scan scratch, then LDS scatter cursors (first KB used)
    __shared__ unsigned lsrt[PT_TILE];  // 64 KB tile-sorted packed edges
    int t = threadIdx.x;
    int e0 = blockIdx.x * PT_TILE;
    int d_reg[PT_EPT];

    for (int i = t; i < KB; i += PT_THREADS) lcnt[i] = 0;
    __syncthreads();
    // pass 1: histogram (cache dst in regs)
    #pragma unroll
    for (int r = 0; r < PT_EPT; r++) {
        int i = e0 + r * PT_THREADS + t;
        if (i < N_EDGES) {
            d_reg[r] = dst[i];
            atomicAdd(&lcnt[d_reg[r] >> 7], 1);
        } else d_reg[r] = -1;
    }
    __syncthreads();
    // exclusive scan of lcnt into cur (Hillis-Steele over 1024 slots)
    int v = (t < KB) ? lcnt[t] : 0;
    cur[t] = v;
    __syncthreads();
    for (int d = 1; d < PT_THREADS; d <<= 1) {
        int add = (t >= d) ? cur[t - d] : 0;
        __syncthreads();
        cur[t] += add;
        __syncthreads();
    }
    cur[t] -= v;  // exclusive
    __syncthreads();
    // reserve global run space: one atomic per (block,bucket)
    for (int b = t; b < KB; b += PT_THREADS) {
        int c = lcnt[b];
        lbase[b] = b * CAP + (c ? atomicAdd(&bcur[b], c) : 0);
    }
    __syncthreads();
    // pass 2: rank-scatter packed edges into LDS (reload src)
    #pragma unroll
    for (int r = 0; r < PT_EPT; r++) {
        int d = d_reg[r];
        if (d >= 0) {
            int i = e0 + r * PT_THREADS + t;
            int p = atomicAdd(&cur[d >> 7], 1);
            lsrt[p] = ((unsigned)src[i] << 7) | (unsigned)(d & (NB - 1));
        }
    }
    __syncthreads();
    // pass 3: burst writeback, one wave per bucket-run, lanes coalesced
    int wv = t >> 6, ln = t & 63;
    for (int b = wv; b < KB; b += PT_WAVES) {
        int c = lcnt[b];
        if (!c) continue;
        int gb = lbase[b];
        int lb = cur[b] - c;                    // run start in LDS
        int lim = (b + 1) * CAP - gb;           // overflow clamp (statistically never)
        int cc = c < lim ? c : lim;
        for (int k = ln; k < cc; k += 64) part[gb + k] = lsrt[lb + k];
    }
}

// ---------------- per-bucket LDS sort -> node-sorted src list (in place) + CSR + dinv ----------------
__global__ __launch_bounds__(512) void k_sort(unsigned* __restrict__ part, const int* __restrict__ bcur,
                                              int* __restrict__ off, int* __restrict__ off_end,
                                              float* __restrict__ dinv) {
    __shared__ int deg[NB];
    __shared__ int sc[NB];
    __shared__ int offl[NB];
    __shared__ int cur[NB];
    __shared__ int lsort[CAP];  // 36 KB
    int b = blockIdx.x, t = threadIdx.x;
    int e0 = b * CAP;
    int cnt = bcur[b];
    if (cnt > CAP) cnt = CAP;
    for (int i = t; i < NB; i += 512) deg[i] = 0;
    __syncthreads();
    // local degree histogram
    for (int i = t; i < cnt; i += 512) atomicAdd(&deg[part[e0 + i] & (NB - 1)], 1);
    __syncthreads();
    // exclusive scan over 128 local nodes
    if (t < NB) sc[t] = deg[t];
    __syncthreads();
    for (int d = 1; d < NB; d <<= 1) {
        int add = (t < NB && t >= d) ? sc[t - d] : 0;
        __syncthreads();
        if (t < NB) sc[t] += add;
        __syncthreads();
    }
    if (t < NB) { int ex = sc[t] - deg[t]; offl[t] = ex; cur[t] = ex; }
    __syncthreads();
    // scatter srcs into LDS at final rank
    for (int i = t; i < cnt; i += 512) {
        unsigned u = part[e0 + i];
        int r = atomicAdd(&cur[u & (NB - 1)], 1);
        lsort[r] = (int)(u >> 7);
    }
    __syncthreads();
    // coalesced writeback (in place)
    for (int i = t; i < cnt; i += 512) part[e0 + i] = (unsigned)lsort[i];
    // node-level CSR + dinv
    if (t < NB) {
        int n = b * NB + t;
        if (n < N_NODES) {
            off[n] = e0 + offl[t];
            off_end[n] = e0 + offl[t] + deg[t];
            dinv[n] = rsqrtf((float)(deg[t] + 1));  // +1 self loop
        }
    }
}

// ---------------- g1 = fp16( dinv * (x @ W1) ) ----------------
__global__ __launch_bounds__(256) void k_gemm1(const float* __restrict__ x, const float* __restrict__ W1,
                                               const float* __restrict__ dinv, __half* __restrict__ g1) {
    __shared__ float Ws[NF * NH];  // 8 KB
    for (int i = threadIdx.x; i < NF * NH; i += 256) Ws[i] = W1[i];
    __syncthreads();
    int gid = blockIdx.x * 256 + threadIdx.x;
    int n = gid >> 4, j = gid & 15;
    if (n >= N_NODES) return;
    const float4* xr = (const float4*)(x + (size_t)n * NF);
    float acc = 0.f;
    #pragma unroll
    for (int k4 = 0; k4 < NF / 4; k4++) {
        float4 v = xr[k4];
        acc += v.x * Ws[(k4 * 4 + 0) * NH + j];
        acc += v.y * Ws[(k4 * 4 + 1) * NH + j];
        acc += v.z * Ws[(k4 * 4 + 2) * NH + j];
        acc += v.w * Ws[(k4 * 4 + 3) * NH + j];
    }
    g1[(size_t)n * NH + j] = __float2half(dinv[n] * acc);
}

// ---- pull aggregate: 1 wave/node, 2 lanes/edge-halfrow, 64 edges/iter, f16 packed accumulate ----
// Reduce tree on VALU: DPP quad_perm(xor1), quad_perm(xor2), row_ror:4, row_ror:8 within 16-lane
// rows (exact for sums), then one xor-16 shfl to combine slot-halves.  Only 4 DS ops remain.
// LAYER1: relu + W2 fused (fp16 out, dinv folded).  LAYER2: sigmoid, f32 out.
__device__ __forceinline__ __half2 shx(__half2 x, int m) {
    union { __half2 h; int i; } u;
    u.h = x;
    u.i = __shfl_xor(u.i, m, 64);
    return u.h;
}

template <int CTRL>
__device__ __forceinline__ __half2 dpp_add(__half2 x) {
    union { __half2 h; int i; } u, r;
    u.h = x;
    r.i = __builtin_amdgcn_update_dpp(0, u.i, CTRL, 0xf, 0xf, true);
    return __hadd2(x, r.h);
}

template <int LAYER>
__global__ __launch_bounds__(256) void k_agg(const __half* __restrict__ g, const int* __restrict__ off,
                                             const int* __restrict__ off_end, const int* __restrict__ sorted,
                                             const float* __restrict__ dinv,
                                             const float* __restrict__ bias, const float* __restrict__ W2,
                                             void* __restrict__ outp) {
    __shared__ __align__(16) unsigned redu[4][8];   // [wave][c*4 + word]: raw f16-pair sums
    __shared__ float redf[4][NH];                   // [wave]: relu row (layer 1)
    __shared__ __align__(16) float W2T[16 * 20];    // W2 transposed, +4 pad
    int t = threadIdx.x;
    if (LAYER == 1) {
        int j = t >> 4, k = t & 15;
        W2T[j * 20 + k] = W2[k * 16 + j];           // W2T[j][k] = W2[k][j]
        __syncthreads();
    }
    int w = t >> 6, lane = t & 63;
    int n = blockIdx.x * 4 + w;                     // grid exact: 25000*4 = 100000
    int slot = lane & 31, c = lane >> 5;            // edge slot, 16B half-row selector
    int o0 = off[n], o1 = off_end[n];
    const char* gbase = (const char*)g + (c << 4);

    // hoisted: self row + dinv (overlap with gather loop)
    int j = lane & 15;
    float dn = dinv[n];
    float selfj = __half2float(g[(size_t)n * NH + j]);

    __half2 a0 = __half2(0.f, 0.f), a1 = a0, a2 = a0, a3 = a0;
    for (int eb = o0; eb < o1; eb += 64) {
        int e1 = eb + slot, e2 = e1 + 32;
        union { uint4 q; __half2 h[4]; } v1, v2;
        v1.q = make_uint4(0u, 0u, 0u, 0u);
        v2.q = make_uint4(0u, 0u, 0u, 0u);
        if (e1 < o1) {
            int s = __builtin_nontemporal_load(&sorted[e1]);
            v1.q = *(const uint4*)(gbase + ((size_t)(unsigned)s << 5));
        }
        if (e2 < o1) {
            int s = __builtin_nontemporal_load(&sorted[e2]);
            v2.q = *(const uint4*)(gbase + ((size_t)(unsigned)s << 5));
        }
        a0 = __hadd2(a0, __hadd2(v1.h[0], v2.h[0]));
        a1 = __hadd2(a1, __hadd2(v1.h[1], v2.h[1]));
        a2 = __hadd2(a2, __hadd2(v1.h[2], v2.h[2]));
        a3 = __hadd2(a3, __hadd2(v1.h[3], v2.h[3]));
    }
    // VALU tree: within-16 stages (xor1, xor2, ror4, ror8) ...
    a0 = dpp_add<0xB1>(a0); a1 = dpp_add<0xB1>(a1); a2 = dpp_add<0xB1>(a2); a3 = dpp_add<0xB1>(a3);
    a0 = dpp_add<0x4E>(a0); a1 = dpp_add<0x4E>(a1); a2 = dpp_add<0x4E>(a2); a3 = dpp_add<0x4E>(a3);
    a0 = dpp_add<0x124>(a0); a1 = dpp_add<0x124>(a1); a2 = dpp_add<0x124>(a2); a3 = dpp_add<0x124>(a3);
    a0 = dpp_add<0x128>(a0); a1 = dpp_add<0x128>(a1); a2 = dpp_add<0x128>(a2); a3 = dpp_add<0x128>(a3);
    // ... then combine slot-halves (lanes 0-15 <-> 16-31 within each c) via xor-16
    a0 = __hadd2(a0, shx(a0, 16));
    a1 = __hadd2(a1, shx(a1, 16));
    a2 = __hadd2(a2, shx(a2, 16));
    a3 = __hadd2(a3, shx(a3, 16));
    // lanes 0 and 32 publish raw words (one ds_write_b128 each)
    if (slot == 0) {
        union { uint4 q; __half2 h[4]; } p;
        p.h[0] = a0; p.h[1] = a1; p.h[2] = a2; p.h[3] = a3;
        *(uint4*)&redu[w][c * 4] = p.q;
    }
    // feature j -> half j>>3, word (j&7)>>1, f16 sel j&1   (same-wave LDS RAW: in-order)
    union { unsigned u; __half2 h; } pick;
    pick.u = redu[w][((j >> 3) << 2) + ((j & 7) >> 1)];
    float sumj = __half2float((j & 1) ? __high2half(pick.h) : __low2half(pick.h));
    if (LAYER == 1) {
        if (lane < NH) {
            redf[w][j] = fmaxf(fmaf(dn, sumj + selfj, bias[j]), 0.f);
            float4 r0 = *(const float4*)&redf[w][0];
            float4 r1 = *(const float4*)&redf[w][4];
            float4 r2 = *(const float4*)&redf[w][8];
            float4 r3 = *(const float4*)&redf[w][12];
            const float* wr = &W2T[j * 20];
            float4 w0 = *(const float4*)&wr[0];
            float4 w1 = *(const float4*)&wr[4];
            float4 w2 = *(const float4*)&wr[8];
            float4 w3 = *(const float4*)&wr[12];
            float h = r0.x * w0.x + r0.y * w0.y + r0.z * w0.z + r0.w * w0.w
                    + r1.x * w1.x + r1.y * w1.y + r1.z * w1.z + r1.w * w1.w
                    + r2.x * w2.x + r2.y * w2.y + r2.z * w2.z + r2.w * w2.w
                    + r3.x * w3.x + r3.y * w3.y + r3.z * w3.z + r3.w * w3.w;
            ((__half*)outp)[(size_t)n * NH + j] = __float2half(dn * h);
        }
    } else {
        if (lane < NH) {
            float z = fmaf(dn, sumj + selfj, bias[j]);
            ((float*)outp)[(size_t)n * NH + j] = 1.f / (1.f + __expf(-z));
        }
    }
}

extern "C" void kernel_launch(void* const* d_in, const int* in_sizes, int n_in,
                              void* d_out, int out_size, void* d_ws, size_t ws_size,
                              hipStream_t stream) {
    const float* x  = (const float*)d_in[0];
    const int* eidx = (const int*)d_in[1];
    const float* W1 = (const float*)d_in[2];
    const float* b1 = (const float*)d_in[3];
    const float* W2 = (const float*)d_in[4];
    const float* b2 = (const float*)d_in[5];
    const int* src = eidx;
    const int* dst = eidx + N_EDGES;
    float* out = (float*)d_out;

    char* ws = (char*)d_ws;
    size_t o = 0;
    auto alloc = [&](size_t bytes) { size_t r = o; o = (o + bytes + 255) & ~(size_t)255; return r; };
    int*      bcur    = (int*)     (ws + alloc(sizeof(int) * KB));
    unsigned* part    = (unsigned*)(ws + alloc(sizeof(unsigned) * (size_t)KB * CAP));  // 28.8 MB
    int*      off     = (int*)     (ws + alloc(sizeof(int) * N_NODES));
    int*      off_end = (int*)     (ws + alloc(sizeof(int) * N_NODES));
    float*    dinv    = (float*)   (ws + alloc(sizeof(float) * N_NODES));
    __half*   g1      = (__half*)  (ws + alloc(sizeof(__half) * N_NODES * NH));
    __half*   g2      = (__half*)  (ws + alloc(sizeof(__half) * N_NODES * NH));
    (void)ws_size; (void)n_in; (void)in_sizes; (void)out_size;

    hipMemsetAsync(bcur, 0, sizeof(int) * KB, stream);

    k_part<<<PT_BLOCKS, PT_THREADS, 0, stream>>>(src, dst, bcur, part);
    k_sort<<<KB, 512, 0, stream>>>(part, bcur, off, off_end, dinv);

    k_gemm1<<<(N_NODES * NH + 255) / 256, 256, 0, stream>>>(x, W1, dinv, g1);

    const int* sorted = (const int*)part;
    k_agg<1><<<N_NODES / 4, 256, 0, stream>>>(g1, off, off_end, sorted, dinv, b1, W2, g2);
    k_agg<2><<<N_NODES / 4, 256, 0, stream>>>(g2, off, off_end, sorted, dinv, b2, nullptr, out);
}

// Round 10
// 190.067 us; speedup vs baseline: 1.0968x; 1.0968x over previous
//
#include <hip/hip_runtime.h>
#include <hip/hip_fp16.h>
#include <math.h>

#define N_NODES 100000
#define N_EDGES 6400000
#define NF 128
#define NH 16
#define NB 128                          // nodes per bucket
#define KB 782                          // ceil(100000/128)
#define CAP 9216                        // static bucket capacity (mean 8192, sd ~90)

#define PT_THREADS 1024
#define PT_EPT 16
#define PT_TILE (PT_THREADS * PT_EPT)   // 16384 edges per block
#define PT_BLOCKS ((N_EDGES + PT_TILE - 1) / PT_TILE)  // 391
#define PT_WAVES (PT_THREADS / 64)      // 16

// ---------------- single-pass partition: LDS multisplit + coalesced burst run writes ----------------
__global__ __launch_bounds__(PT_THREADS) void k_part(const int* __restrict__ src, const int* __restrict__ dst,
                                                     int* __restrict__ bcur, unsigned* __restrict__ part) {
    __shared__ int lcnt[KB];            // per-bucket count in this tile
    __shared__ int lbase[KB];           // global write base (absolute)
    __shared__ int cur[PT_THREADS];     // scan scratch, then LDS scatter cursors (first KB used)
    __shared__ unsigned lsrt[PT_TILE];  // 64 KB tile-sorted packed edges
    int t = threadIdx.x;
    int e0 = blockIdx.x * PT_TILE;
    int d_reg[PT_EPT];

    for (int i = t; i < KB; i += PT_THREADS) lcnt[i] = 0;
    __syncthreads();
    // pass 1: histogram (cache dst in regs)
    #pragma unroll
    for (int r = 0; r < PT_EPT; r++) {
        int i = e0 + r * PT_THREADS + t;
        if (i < N_EDGES) {
            d_reg[r] = dst[i];
            atomicAdd(&lcnt[d_reg[r] >> 7], 1);
        } else d_reg[r] = -1;
    }
    __syncthreads();
    // exclusive scan of lcnt into cur (Hillis-Steele over 1024 slots)
    int v = (t < KB) ? lcnt[t] : 0;
    cur[t] = v;
    __syncthreads();
    for (int d = 1; d < PT_THREADS; d <<= 1) {
        int add = (t >= d) ? cur[t - d] : 0;
        __syncthreads();
        cur[t] += add;
        __syncthreads();
    }
    cur[t] -= v;  // exclusive
    __syncthreads();
    // reserve global run space: one atomic per (block,bucket)
    for (int b = t; b < KB; b += PT_THREADS) {
        int c = lcnt[b];
        lbase[b] = b * CAP + (c ? atomicAdd(&bcur[b], c) : 0);
    }
    __syncthreads();
    // pass 2: rank-scatter packed edges into LDS (reload src)
    #pragma unroll
    for (int r = 0; r < PT_EPT; r++) {
        int d = d_reg[r];
        if (d >= 0) {
            int i = e0 + r * PT_THREADS + t;
            int p = atomicAdd(&cur[d >> 7], 1);
            lsrt[p] = ((unsigned)src[i] << 7) | (unsigned)(d & (NB - 1));
        }
    }
    __syncthreads();
    // pass 3: burst writeback, one wave per bucket-run, lanes coalesced
    int wv = t >> 6, ln = t & 63;
    for (int b = wv; b < KB; b += PT_WAVES) {
        int c = lcnt[b];
        if (!c) continue;
        int gb = lbase[b];
        int lb = cur[b] - c;                    // run start in LDS
        int lim = (b + 1) * CAP - gb;           // overflow clamp (statistically never)
        int cc = c < lim ? c : lim;
        for (int k = ln; k < cc; k += 64) part[gb + k] = lsrt[lb + k];
    }
}

// ---------------- per-bucket LDS sort -> node-sorted src list (in place) + CSR + dinv ----------------
__global__ __launch_bounds__(512) void k_sort(unsigned* __restrict__ part, const int* __restrict__ bcur,
                                              int* __restrict__ off, int* __restrict__ off_end,
                                              float* __restrict__ dinv) {
    __shared__ int deg[NB];
    __shared__ int sc[NB];
    __shared__ int offl[NB];
    __shared__ int cur[NB];
    __shared__ int lsort[CAP];  // 36 KB
    int b = blockIdx.x, t = threadIdx.x;
    int e0 = b * CAP;
    int cnt = bcur[b];
    if (cnt > CAP) cnt = CAP;
    for (int i = t; i < NB; i += 512) deg[i] = 0;
    __syncthreads();
    // local degree histogram
    for (int i = t; i < cnt; i += 512) atomicAdd(&deg[part[e0 + i] & (NB - 1)], 1);
    __syncthreads();
    // exclusive scan over 128 local nodes
    if (t < NB) sc[t] = deg[t];
    __syncthreads();
    for (int d = 1; d < NB; d <<= 1) {
        int add = (t < NB && t >= d) ? sc[t - d] : 0;
        __syncthreads();
        if (t < NB) sc[t] += add;
        __syncthreads();
    }
    if (t < NB) { int ex = sc[t] - deg[t]; offl[t] = ex; cur[t] = ex; }
    __syncthreads();
    // scatter srcs into LDS at final rank
    for (int i = t; i < cnt; i += 512) {
        unsigned u = part[e0 + i];
        int r = atomicAdd(&cur[u & (NB - 1)], 1);
        lsort[r] = (int)(u >> 7);
    }
    __syncthreads();
    // coalesced writeback (in place)
    for (int i = t; i < cnt; i += 512) part[e0 + i] = (unsigned)lsort[i];
    // node-level CSR + dinv
    if (t < NB) {
        int n = b * NB + t;
        if (n < N_NODES) {
            off[n] = e0 + offl[t];
            off_end[n] = e0 + offl[t] + deg[t];
            dinv[n] = rsqrtf((float)(deg[t] + 1));  // +1 self loop
        }
    }
}

// ---------------- g1 = fp16( dinv * (x @ W1) ) ----------------
__global__ __launch_bounds__(256) void k_gemm1(const float* __restrict__ x, const float* __restrict__ W1,
                                               const float* __restrict__ dinv, __half* __restrict__ g1) {
    __shared__ float Ws[NF * NH];  // 8 KB
    for (int i = threadIdx.x; i < NF * NH; i += 256) Ws[i] = W1[i];
    __syncthreads();
    int gid = blockIdx.x * 256 + threadIdx.x;
    int n = gid >> 4, j = gid & 15;
    if (n >= N_NODES) return;
    const float4* xr = (const float4*)(x + (size_t)n * NF);
    float acc = 0.f;
    #pragma unroll
    for (int k4 = 0; k4 < NF / 4; k4++) {
        float4 v = xr[k4];
        acc += v.x * Ws[(k4 * 4 + 0) * NH + j];
        acc += v.y * Ws[(k4 * 4 + 1) * NH + j];
        acc += v.z * Ws[(k4 * 4 + 2) * NH + j];
        acc += v.w * Ws[(k4 * 4 + 3) * NH + j];
    }
    g1[(size_t)n * NH + j] = __float2half(dinv[n] * acc);
}

// ---- pull aggregate: 1 wave/node, 2 lanes/edge-halfrow, 128 edges/iter (4 slots/lane),
// f16 packed accumulate, bpermute shuffle tree (R8-proven).  8 VMEM in flight per lane.
// LAYER1: relu + W2 fused (fp16 out, dinv folded).  LAYER2: sigmoid, f32 out.
__device__ __forceinline__ __half2 shx(__half2 x, int m) {
    union { __half2 h; int i; } u;
    u.h = x;
    u.i = __shfl_xor(u.i, m, 64);
    return u.h;
}

template <int LAYER>
__global__ __launch_bounds__(256) void k_agg(const __half* __restrict__ g, const int* __restrict__ off,
                                             const int* __restrict__ off_end, const int* __restrict__ sorted,
                                             const float* __restrict__ dinv,
                                             const float* __restrict__ bias, const float* __restrict__ W2,
                                             void* __restrict__ outp) {
    __shared__ __align__(16) unsigned redu[4][8];   // [wave][c*4 + word]: raw f16-pair sums
    __shared__ float redf[4][NH];                   // [wave]: relu row (layer 1)
    __shared__ __align__(16) float W2T[16 * 20];    // W2 transposed, +4 pad
    int t = threadIdx.x;
    if (LAYER == 1) {
        int j = t >> 4, k = t & 15;
        W2T[j * 20 + k] = W2[k * 16 + j];           // W2T[j][k] = W2[k][j]
        __syncthreads();
    }
    int w = t >> 6, lane = t & 63;
    int n = blockIdx.x * 4 + w;                     // grid exact: 25000*4 = 100000
    int slot = lane & 31, c = lane >> 5;            // edge slot, 16B half-row selector
    int o0 = off[n], o1 = off_end[n];
    const char* gbase = (const char*)g + (c << 4);

    // hoisted: self row + dinv (overlap with gather loop)
    int j = lane & 15;
    float dn = dinv[n];
    float selfj = __half2float(g[(size_t)n * NH + j]);

    __half2 a0 = __half2(0.f, 0.f), a1 = a0, a2 = a0, a3 = a0;
    for (int eb = o0; eb < o1; eb += 128) {
        int e1 = eb + slot, e2 = e1 + 32, e3 = e1 + 64, e4 = e1 + 96;
        union { uint4 q; __half2 h[4]; } v1, v2, v3, v4;
        v1.q = make_uint4(0u, 0u, 0u, 0u);
        v2.q = make_uint4(0u, 0u, 0u, 0u);
        v3.q = make_uint4(0u, 0u, 0u, 0u);
        v4.q = make_uint4(0u, 0u, 0u, 0u);
        if (e1 < o1) {
            int s = sorted[e1];
            v1.q = *(const uint4*)(gbase + ((size_t)(unsigned)s << 5));
        }
        if (e2 < o1) {
            int s = sorted[e2];
            v2.q = *(const uint4*)(gbase + ((size_t)(unsigned)s << 5));
        }
        if (e3 < o1) {
            int s = sorted[e3];
            v3.q = *(const uint4*)(gbase + ((size_t)(unsigned)s << 5));
        }
        if (e4 < o1) {
            int s = sorted[e4];
            v4.q = *(const uint4*)(gbase + ((size_t)(unsigned)s << 5));
        }
        a0 = __hadd2(a0, __hadd2(__hadd2(v1.h[0], v2.h[0]), __hadd2(v3.h[0], v4.h[0])));
        a1 = __hadd2(a1, __hadd2(__hadd2(v1.h[1], v2.h[1]), __hadd2(v3.h[1], v4.h[1])));
        a2 = __hadd2(a2, __hadd2(__hadd2(v1.h[2], v2.h[2]), __hadd2(v3.h[2], v4.h[2])));
        a3 = __hadd2(a3, __hadd2(__hadd2(v1.h[3], v2.h[3]), __hadd2(v3.h[3], v4.h[3])));
    }
    // 5-stage tree over each 32-lane half (xor masks < 32 keep halves separate)
    #pragma unroll
    for (int m = 1; m <= 16; m <<= 1) {
        a0 = __hadd2(a0, shx(a0, m));
        a1 = __hadd2(a1, shx(a1, m));
        a2 = __hadd2(a2, shx(a2, m));
        a3 = __hadd2(a3, shx(a3, m));
    }
    // lanes 0 and 32 publish raw words (one ds_write_b128 each)
    if (slot == 0) {
        union { uint4 q; __half2 h[4]; } p;
        p.h[0] = a0; p.h[1] = a1; p.h[2] = a2; p.h[3] = a3;
        *(uint4*)&redu[w][c * 4] = p.q;
    }
    // feature j -> half j>>3, word (j&7)>>1, f16 sel j&1   (same-wave LDS RAW: in-order)
    union { unsigned u; __half2 h; } pick;
    pick.u = redu[w][((j >> 3) << 2) + ((j & 7) >> 1)];
    float sumj = __half2float((j & 1) ? __high2half(pick.h) : __low2half(pick.h));
    if (LAYER == 1) {
        if (lane < NH) {
            redf[w][j] = fmaxf(fmaf(dn, sumj + selfj, bias[j]), 0.f);
            float4 r0 = *(const float4*)&redf[w][0];
            float4 r1 = *(const float4*)&redf[w][4];
            float4 r2 = *(const float4*)&redf[w][8];
            float4 r3 = *(const float4*)&redf[w][12];
            const float* wr = &W2T[j * 20];
            float4 w0 = *(const float4*)&wr[0];
            float4 w1 = *(const float4*)&wr[4];
            float4 w2 = *(const float4*)&wr[8];
            float4 w3 = *(const float4*)&wr[12];
            float h = r0.x * w0.x + r0.y * w0.y + r0.z * w0.z + r0.w * w0.w
                    + r1.x * w1.x + r1.y * w1.y + r1.z * w1.z + r1.w * w1.w
                    + r2.x * w2.x + r2.y * w2.y + r2.z * w2.z + r2.w * w2.w
                    + r3.x * w3.x + r3.y * w3.y + r3.z * w3.z + r3.w * w3.w;
            ((__half*)outp)[(size_t)n * NH + j] = __float2half(dn * h);
        }
    } else {
        if (lane < NH) {
            float z = fmaf(dn, sumj + selfj, bias[j]);
            ((float*)outp)[(size_t)n * NH + j] = 1.f / (1.f + __expf(-z));
        }
    }
}

extern "C" void kernel_launch(void* const* d_in, const int* in_sizes, int n_in,
                              void* d_out, int out_size, void* d_ws, size_t ws_size,
                              hipStream_t stream) {
    const float* x  = (const float*)d_in[0];
    const int* eidx = (const int*)d_in[1];
    const float* W1 = (const float*)d_in[2];
    const float* b1 = (const float*)d_in[3];
    const float* W2 = (const float*)d_in[4];
    const float* b2 = (const float*)d_in[5];
    const int* src = eidx;
    const int* dst = eidx + N_EDGES;
    float* out = (float*)d_out;

    char* ws = (char*)d_ws;
    size_t o = 0;
    auto alloc = [&](size_t bytes) { size_t r = o; o = (o + bytes + 255) & ~(size_t)255; return r; };
    int*      bcur    = (int*)     (ws + alloc(sizeof(int) * KB));
    unsigned* part    = (unsigned*)(ws + alloc(sizeof(unsigned) * (size_t)KB * CAP));  // 28.8 MB
    int*      off     = (int*)     (ws + alloc(sizeof(int) * N_NODES));
    int*      off_end = (int*)     (ws + alloc(sizeof(int) * N_NODES));
    float*    dinv    = (float*)   (ws + alloc(sizeof(float) * N_NODES));
    __half*   g1      = (__half*)  (ws + alloc(sizeof(__half) * N_NODES * NH));
    __half*   g2      = (__half*)  (ws + alloc(sizeof(__half) * N_NODES * NH));
    (void)ws_size; (void)n_in; (void)in_sizes; (void)out_size;

    hipMemsetAsync(bcur, 0, sizeof(int) * KB, stream);

    k_part<<<PT_BLOCKS, PT_THREADS, 0, stream>>>(src, dst, bcur, part);
    k_sort<<<KB, 512, 0, stream>>>(part, bcur, off, off_end, dinv);

    k_gemm1<<<(N_NODES * NH + 255) / 256, 256, 0, stream>>>(x, W1, dinv, g1);

    const int* sorted = (const int*)part;
    k_agg<1><<<N_NODES / 4, 256, 0, stream>>>(g1, off, off_end, sorted, dinv, b1, W2, g2);
    k_agg<2><<<N_NODES / 4, 256, 0, stream>>>(g2, off, off_end, sorted, dinv, b2, nullptr, out);
}

// Round 11
// 189.365 us; speedup vs baseline: 1.1009x; 1.0037x over previous
//
#include <hip/hip_runtime.h>
#include <hip/hip_fp16.h>
#include <math.h>

#define N_NODES 100000
#define N_EDGES 6400000
#define NF 128
#define NH 16
#define NB 128                          // nodes per bucket
#define KB 782                          // ceil(100000/128)
#define CAP 9216                        // static bucket capacity (mean 8192, sd ~90)

#define PT_THREADS 1024
#define PT_EPT 16
#define PT_TILE (PT_THREADS * PT_EPT)   // 16384 edges per block
#define PT_BLOCKS ((N_EDGES + PT_TILE - 1) / PT_TILE)  // 391
#define PT_WAVES (PT_THREADS / 64)      // 16

typedef __attribute__((ext_vector_type(4))) unsigned uv4;

// ---------------- single-pass partition: LDS multisplit + coalesced burst run writes ----------------
// Scan over KB buckets is wave-shuffle based: 3 block barriers total (was 21).
__global__ __launch_bounds__(PT_THREADS) void k_part(const int* __restrict__ src, const int* __restrict__ dst,
                                                     int* __restrict__ bcur, unsigned* __restrict__ part) {
    __shared__ int lcnt[KB];            // per-bucket count in this tile
    __shared__ int lbase[KB];           // global write base (absolute)
    __shared__ int cur[KB];             // LDS scatter cursors
    __shared__ int wsum[PT_WAVES];
    __shared__ int woff[PT_WAVES];
    __shared__ unsigned lsrt[PT_TILE];  // 64 KB tile-sorted packed edges
    int t = threadIdx.x;
    int e0 = blockIdx.x * PT_TILE;
    int d_reg[PT_EPT];

    for (int i = t; i < KB; i += PT_THREADS) lcnt[i] = 0;
    __syncthreads();
    // pass 1: histogram (cache dst in regs)
    #pragma unroll
    for (int r = 0; r < PT_EPT; r++) {
        int i = e0 + r * PT_THREADS + t;
        if (i < N_EDGES) {
            d_reg[r] = dst[i];
            atomicAdd(&lcnt[d_reg[r] >> 7], 1);
        } else d_reg[r] = -1;
    }
    __syncthreads();
    // wave-shuffle exclusive scan of lcnt[0..KB)
    int lane_ = t & 63, wv_ = t >> 6;
    int v = (t < KB) ? lcnt[t] : 0;
    int inc = v;
    #pragma unroll
    for (int d = 1; d < 64; d <<= 1) {
        int u = __shfl_up(inc, d, 64);
        if (lane_ >= d) inc += u;
    }
    if (lane_ == 63) wsum[wv_] = inc;
    __syncthreads();
    if (t < PT_WAVES) {
        int s = 0;
        for (int k = 0; k < t; k++) s += wsum[k];
        woff[t] = s;
    }
    __syncthreads();
    if (t < KB) cur[t] = inc - v + woff[wv_];   // exclusive scan result
    // reserve global run space: one atomic per (block,bucket)
    for (int b = t; b < KB; b += PT_THREADS) {
        int c = lcnt[b];
        lbase[b] = b * CAP + (c ? atomicAdd(&bcur[b], c) : 0);
    }
    __syncthreads();
    // pass 2: rank-scatter packed edges into LDS (reload src)
    #pragma unroll
    for (int r = 0; r < PT_EPT; r++) {
        int d = d_reg[r];
        if (d >= 0) {
            int i = e0 + r * PT_THREADS + t;
            int p = atomicAdd(&cur[d >> 7], 1);
            lsrt[p] = ((unsigned)src[i] << 7) | (unsigned)(d & (NB - 1));
        }
    }
    __syncthreads();
    // pass 3: burst writeback, one wave per bucket-run, lanes coalesced
    int wv = t >> 6, ln = t & 63;
    for (int b = wv; b < KB; b += PT_WAVES) {
        int c = lcnt[b];
        if (!c) continue;
        int gb = lbase[b];
        int lb = cur[b] - c;                    // run start in LDS
        int lim = (b + 1) * CAP - gb;           // overflow clamp (statistically never)
        int cc = c < lim ? c : lim;
        for (int k = ln; k < cc; k += 64) part[gb + k] = lsrt[lb + k];
    }
}

// ---------------- per-bucket LDS sort -> node-sorted src list (in place) + CSR + dinv ----------------
__global__ __launch_bounds__(512) void k_sort(unsigned* __restrict__ part, const int* __restrict__ bcur,
                                              int* __restrict__ off, int* __restrict__ off_end,
                                              float* __restrict__ dinv) {
    __shared__ int deg[NB];
    __shared__ int sc[NB];
    __shared__ int offl[NB];
    __shared__ int cur[NB];
    __shared__ int lsort[CAP];  // 36 KB
    int b = blockIdx.x, t = threadIdx.x;
    int e0 = b * CAP;
    int cnt = bcur[b];
    if (cnt > CAP) cnt = CAP;
    for (int i = t; i < NB; i += 512) deg[i] = 0;
    __syncthreads();
    // local degree histogram
    for (int i = t; i < cnt; i += 512) atomicAdd(&deg[part[e0 + i] & (NB - 1)], 1);
    __syncthreads();
    // exclusive scan over 128 local nodes
    if (t < NB) sc[t] = deg[t];
    __syncthreads();
    for (int d = 1; d < NB; d <<= 1) {
        int add = (t < NB && t >= d) ? sc[t - d] : 0;
        __syncthreads();
        if (t < NB) sc[t] += add;
        __syncthreads();
    }
    if (t < NB) { int ex = sc[t] - deg[t]; offl[t] = ex; cur[t] = ex; }
    __syncthreads();
    // scatter srcs into LDS at final rank
    for (int i = t; i < cnt; i += 512) {
        unsigned u = part[e0 + i];
        int r = atomicAdd(&cur[u & (NB - 1)], 1);
        lsort[r] = (int)(u >> 7);
    }
    __syncthreads();
    // coalesced writeback (in place)
    for (int i = t; i < cnt; i += 512) part[e0 + i] = (unsigned)lsort[i];
    // node-level CSR + dinv
    if (t < NB) {
        int n = b * NB + t;
        if (n < N_NODES) {
            off[n] = e0 + offl[t];
            off_end[n] = e0 + offl[t] + deg[t];
            dinv[n] = rsqrtf((float)(deg[t] + 1));  // +1 self loop
        }
    }
}

// ---------------- g1 = fp16( dinv * (x @ W1) ) ----------------
__global__ __launch_bounds__(256) void k_gemm1(const float* __restrict__ x, const float* __restrict__ W1,
                                               const float* __restrict__ dinv, __half* __restrict__ g1) {
    __shared__ float Ws[NF * NH];  // 8 KB
    for (int i = threadIdx.x; i < NF * NH; i += 256) Ws[i] = W1[i];
    __syncthreads();
    int gid = blockIdx.x * 256 + threadIdx.x;
    int n = gid >> 4, j = gid & 15;
    if (n >= N_NODES) return;
    const float4* xr = (const float4*)(x + (size_t)n * NF);
    float acc = 0.f;
    #pragma unroll
    for (int k4 = 0; k4 < NF / 4; k4++) {
        float4 v = xr[k4];
        acc += v.x * Ws[(k4 * 4 + 0) * NH + j];
        acc += v.y * Ws[(k4 * 4 + 1) * NH + j];
        acc += v.z * Ws[(k4 * 4 + 2) * NH + j];
        acc += v.w * Ws[(k4 * 4 + 3) * NH + j];
    }
    g1[(size_t)n * NH + j] = __float2half(dinv[n] * acc);
}

// ---- pull aggregate: 1 wave/node, 2 lanes/edge-halfrow, 128 edges/iter (4 slots/lane) ----
// Gathers via SRSRC buffer_load_dwordx4 (32-bit voffset, 1 VALU addr); OOB slots use a
// sentinel index (1<<26) whose voffset exceeds num_records -> HW returns 0 (no exec-mask
// dance, no zero-init, no data cndmask).  part[] is padded so index loads are unconditional.
// LAYER1: relu + W2 fused (fp16 out, dinv folded).  LAYER2: sigmoid, f32 out.
__device__ __forceinline__ __half2 shx(__half2 x, int m) {
    union { __half2 h; int i; } u;
    u.h = x;
    u.i = __shfl_xor(u.i, m, 64);
    return u.h;
}

__device__ __forceinline__ uv4 make_srd(const void* p, unsigned bytes) {
    union { const void* q; unsigned u[2]; } a; a.q = p;
    uv4 r;
    r.x = a.u[0];
    r.y = a.u[1];
    r.z = bytes;          // num_records (stride==0): bytes
    r.w = 0x00020000u;    // raw dword access
    return r;
}

template <int LAYER>
__global__ __launch_bounds__(256) void k_agg(const __half* __restrict__ g, const int* __restrict__ off,
                                             const int* __restrict__ off_end,
                                             const unsigned* __restrict__ sorted,
                                             const float* __restrict__ dinv,
                                             const float* __restrict__ bias, const float* __restrict__ W2,
                                             void* __restrict__ outp) {
    __shared__ __align__(16) unsigned redu[4][8];   // [wave][c*4 + word]: raw f16-pair sums
    __shared__ float redf[4][NH];                   // [wave]: relu row (layer 1)
    __shared__ __align__(16) float W2T[16 * 20];    // W2 transposed, +4 pad
    int t = threadIdx.x;
    if (LAYER == 1) {
        int j = t >> 4, k = t & 15;
        W2T[j * 20 + k] = W2[k * 16 + j];           // W2T[j][k] = W2[k][j]
        __syncthreads();
    }
    int w = t >> 6, lane = t & 63;
    int n = blockIdx.x * 4 + w;                     // grid exact: 25000*4 = 100000
    int slot = lane & 31, c = lane >> 5;            // edge slot, 16B half-row selector
    int o0 = off[n], o1 = off_end[n];

    const uv4 srd = make_srd(g, (unsigned)(N_NODES * NH * sizeof(__half)));
    unsigned cofs = (unsigned)(c << 4);

    // hoisted: self row + dinv (overlap with gather loop)
    int j = lane & 15;
    float dn = dinv[n];
    float selfj = __half2float(g[(size_t)n * NH + j]);

    union HV { uv4 q; __half2 h[4]; };
    __half2 a0 = __half2(0.f, 0.f), a1 = a0, a2 = a0, a3 = a0;
    for (int eb = o0; eb < o1; eb += 128) {
        int e1 = eb + slot;
        unsigned s1 = sorted[e1];
        unsigned s2 = sorted[e1 + 32];
        unsigned s3 = sorted[e1 + 64];
        unsigned s4 = sorted[e1 + 96];
        if (e1      >= o1) s1 = 1u << 26;   // sentinel -> buffer OOB -> returns 0
        if (e1 + 32 >= o1) s2 = 1u << 26;
        if (e1 + 64 >= o1) s3 = 1u << 26;
        if (e1 + 96 >= o1) s4 = 1u << 26;
        unsigned f1 = (s1 << 5) + cofs;
        unsigned f2 = (s2 << 5) + cofs;
        unsigned f3 = (s3 << 5) + cofs;
        unsigned f4 = (s4 << 5) + cofs;
        HV v1, v2, v3, v4;
        asm volatile("buffer_load_dwordx4 %0, %1, %2, 0 offen" : "=v"(v1.q) : "v"(f1), "s"(srd));
        asm volatile("buffer_load_dwordx4 %0, %1, %2, 0 offen" : "=v"(v2.q) : "v"(f2), "s"(srd));
        asm volatile("buffer_load_dwordx4 %0, %1, %2, 0 offen" : "=v"(v3.q) : "v"(f3), "s"(srd));
        asm volatile("buffer_load_dwordx4 %0, %1, %2, 0 offen" : "=v"(v4.q) : "v"(f4), "s"(srd));
        asm volatile("s_waitcnt vmcnt(0)" ::: "memory");
        __builtin_amdgcn_sched_barrier(0);          // rule #18: pin reg-only ops after waitcnt
        a0 = __hadd2(a0, __hadd2(__hadd2(v1.h[0], v2.h[0]), __hadd2(v3.h[0], v4.h[0])));
        a1 = __hadd2(a1, __hadd2(__hadd2(v1.h[1], v2.h[1]), __hadd2(v3.h[1], v4.h[1])));
        a2 = __hadd2(a2, __hadd2(__hadd2(v1.h[2], v2.h[2]), __hadd2(v3.h[2], v4.h[2])));
        a3 = __hadd2(a3, __hadd2(__hadd2(v1.h[3], v2.h[3]), __hadd2(v3.h[3], v4.h[3])));
    }
    // 5-stage tree over each 32-lane half (xor masks < 32 keep halves separate)
    #pragma unroll
    for (int m = 1; m <= 16; m <<= 1) {
        a0 = __hadd2(a0, shx(a0, m));
        a1 = __hadd2(a1, shx(a1, m));
        a2 = __hadd2(a2, shx(a2, m));
        a3 = __hadd2(a3, shx(a3, m));
    }
    // lanes 0 and 32 publish raw words (one ds_write_b128 each)
    if (slot == 0) {
        union { uint4 q; __half2 h[4]; } p;
        p.h[0] = a0; p.h[1] = a1; p.h[2] = a2; p.h[3] = a3;
        *(uint4*)&redu[w][c * 4] = p.q;
    }
    // feature j -> half j>>3, word (j&7)>>1, f16 sel j&1   (same-wave LDS RAW: in-order)
    union { unsigned u; __half2 h; } pick;
    pick.u = redu[w][((j >> 3) << 2) + ((j & 7) >> 1)];
    float sumj = __half2float((j & 1) ? __high2half(pick.h) : __low2half(pick.h));
    if (LAYER == 1) {
        if (lane < NH) {
            redf[w][j] = fmaxf(fmaf(dn, sumj + selfj, bias[j]), 0.f);
            float4 r0 = *(const float4*)&redf[w][0];
            float4 r1 = *(const float4*)&redf[w][4];
            float4 r2 = *(const float4*)&redf[w][8];
            float4 r3 = *(const float4*)&redf[w][12];
            const float* wr = &W2T[j * 20];
            float4 w0 = *(const float4*)&wr[0];
            float4 w1 = *(const float4*)&wr[4];
            float4 w2 = *(const float4*)&wr[8];
            float4 w3 = *(const float4*)&wr[12];
            float h = r0.x * w0.x + r0.y * w0.y + r0.z * w0.z + r0.w * w0.w
                    + r1.x * w1.x + r1.y * w1.y + r1.z * w1.z + r1.w * w1.w
                    + r2.x * w2.x + r2.y * w2.y + r2.z * w2.z + r2.w * w2.w
                    + r3.x * w3.x + r3.y * w3.y + r3.z * w3.z + r3.w * w3.w;
            ((__half*)outp)[(size_t)n * NH + j] = __float2half(dn * h);
        }
    } else {
        if (lane < NH) {
            float z = fmaf(dn, sumj + selfj, bias[j]);
            ((float*)outp)[(size_t)n * NH + j] = 1.f / (1.f + __expf(-z));
        }
    }
}

extern "C" void kernel_launch(void* const* d_in, const int* in_sizes, int n_in,
                              void* d_out, int out_size, void* d_ws, size_t ws_size,
                              hipStream_t stream) {
    const float* x  = (const float*)d_in[0];
    const int* eidx = (const int*)d_in[1];
    const float* W1 = (const float*)d_in[2];
    const float* b1 = (const float*)d_in[3];
    const float* W2 = (const float*)d_in[4];
    const float* b2 = (const float*)d_in[5];
    const int* src = eidx;
    const int* dst = eidx + N_EDGES;
    float* out = (float*)d_out;

    char* ws = (char*)d_ws;
    size_t o = 0;
    auto alloc = [&](size_t bytes) { size_t r = o; o = (o + bytes + 255) & ~(size_t)255; return r; };
    int*      bcur    = (int*)     (ws + alloc(sizeof(int) * KB));
    unsigned* part    = (unsigned*)(ws + alloc(sizeof(unsigned) * ((size_t)KB * CAP + 512)));  // +pad for unconditional idx loads
    int*      off     = (int*)     (ws + alloc(sizeof(int) * N_NODES));
    int*      off_end = (int*)     (ws + alloc(sizeof(int) * N_NODES));
    float*    dinv    = (float*)   (ws + alloc(sizeof(float) * N_NODES));
    __half*   g1      = (__half*)  (ws + alloc(sizeof(__half) * N_NODES * NH));
    __half*   g2      = (__half*)  (ws + alloc(sizeof(__half) * N_NODES * NH));
    (void)ws_size; (void)n_in; (void)in_sizes; (void)out_size;

    hipMemsetAsync(bcur, 0, sizeof(int) * KB, stream);

    k_part<<<PT_BLOCKS, PT_THREADS, 0, stream>>>(src, dst, bcur, part);
    k_sort<<<KB, 512, 0, stream>>>(part, bcur, off, off_end, dinv);

    k_gemm1<<<(N_NODES * NH + 255) / 256, 256, 0, stream>>>(x, W1, dinv, g1);

    k_agg<1><<<N_NODES / 4, 256, 0, stream>>>(g1, off, off_end, part, dinv, b1, W2, g2);
    k_agg<2><<<N_NODES / 4, 256, 0, stream>>>(g2, off, off_end, part, dinv, b2, nullptr, out);
}